// Round 5
// baseline (302.561 us; speedup 1.0000x reference)
//
#include <hip/hip_runtime.h>
#include <math.h>

typedef __attribute__((ext_vector_type(4))) float f32x4;
typedef __attribute__((ext_vector_type(8))) short bf16x8;

// Problem constants
#define NB 16
#define NT 2048
#define NMEL 80
#define NPOS 512          // stacked positions per batch
#define EDIM 16
#define NEMB 8192
#define ENCD 512
#define MROWS (NB*511)    // 8176 logit rows
#define MPAD 8192
#define NVT 32            // 8192 / 256 col tiles

__device__ __forceinline__ unsigned short f2bf(float x) {
    union { float f; unsigned u; } v; v.f = x;
    unsigned r = v.u + 0x7fffu + ((v.u >> 16) & 1u);
    return (unsigned short)(r >> 16);
}

__device__ __forceinline__ void gl_lds16(const void* gsrc, void* lds) {
    __builtin_amdgcn_global_load_lds(
        (const __attribute__((address_space(1))) unsigned int*)gsrc,
        (__attribute__((address_space(3))) unsigned int*)lds,
        16, 0, 0);
}

// ---------------- Kernel A: codes (stack -> LN -> proj -> normalize -> argmin) ----
// Blocks 0..31 zero presence; block 32 zeroes sctrl/partials.
__global__ __launch_bounds__(256) void codes_kernel(
    const float* __restrict__ feats, const float* __restrict__ proj,
    const float* __restrict__ emb, int* __restrict__ codes,
    int* __restrict__ presence, int* __restrict__ sctrl)
{
    __shared__ float embS[512][EDIM + 1];   // col 16 = 0.5*||e||^2
    const int tid  = threadIdx.x;
    const int lane = tid & 63;
    const int wave = tid >> 6;
    const int gbase = blockIdx.x * 16 + wave * 4;

    if (blockIdx.x < 32) presence[blockIdx.x * 256 + tid] = 0;
    if (blockIdx.x == 32 && tid < 160) sctrl[tid] = 0;   // ticket, uniq, partials

    float yn[4][EDIM];

    #pragma unroll
    for (int pi = 0; pi < 4; ++pi) {
        const int g = gbase + pi;
        const int b = g >> 9;
        const int i = g & 511;
        float xv[5];
        float s = 0.f, sq = 0.f;
        #pragma unroll
        for (int qq = 0; qq < 5; ++qq) {
            const int d = lane + 64 * qq;
            const int j = d / 80, k = d - j * 80;
            const float v = feats[((b * NT) + (i * 4 + j)) * NMEL + k];
            xv[qq] = v; s += v; sq += v * v;
        }
        for (int m = 1; m < 64; m <<= 1) { s += __shfl_xor(s, m); sq += __shfl_xor(sq, m); }
        const float mean = s * (1.0f / 320.0f);
        const float var  = sq * (1.0f / 320.0f) - mean * mean;
        const float rstd = rsqrtf(var + 1e-6f);

        float acc[EDIM];
        #pragma unroll
        for (int e = 0; e < EDIM; ++e) acc[e] = 0.f;
        #pragma unroll
        for (int qq = 0; qq < 5; ++qq) {
            const int d = lane + 64 * qq;
            const float xn = (xv[qq] - mean) * rstd;
            #pragma unroll
            for (int e = 0; e < EDIM; ++e) acc[e] += xn * proj[d * EDIM + e];
        }
        for (int m = 1; m < 64; m <<= 1) {
            #pragma unroll
            for (int e = 0; e < EDIM; ++e) acc[e] += __shfl_xor(acc[e], m);
        }
        float nsq = 0.f;
        #pragma unroll
        for (int e = 0; e < EDIM; ++e) nsq += acc[e] * acc[e];
        const float inv = 1.0f / (sqrtf(nsq) + 1e-8f);
        #pragma unroll
        for (int e = 0; e < EDIM; ++e) yn[pi][e] = acc[e] * inv;
    }

    float mind[4]; int mini[4];
    #pragma unroll
    for (int pi = 0; pi < 4; ++pi) { mind[pi] = INFINITY; mini[pi] = 0x7fffffff; }

    for (int c = 0; c < 16; ++c) {
        __syncthreads();
        #pragma unroll
        for (int r = 0; r < 32; ++r) {
            const int flat = r * 256 + tid;
            const int vl = flat >> 4, e = flat & 15;
            embS[vl][e] = emb[c * 8192 + flat];
        }
        __syncthreads();
        #pragma unroll
        for (int rr = 0; rr < 2; ++rr) {
            const int vl = tid * 2 + rr;
            float e2 = 0.f;
            #pragma unroll
            for (int e = 0; e < EDIM; ++e) e2 += embS[vl][e] * embS[vl][e];
            embS[vl][EDIM] = 0.5f * e2;
        }
        __syncthreads();
        #pragma unroll
        for (int qq = 0; qq < 8; ++qq) {
            const int vl = lane + 64 * qq;
            float ev[EDIM];
            #pragma unroll
            for (int e = 0; e < EDIM; ++e) ev[e] = embS[vl][e];
            const float h2 = embS[vl][EDIM];
            const int v = c * 512 + vl;
            #pragma unroll
            for (int pi = 0; pi < 4; ++pi) {
                float dot = 0.f;
                #pragma unroll
                for (int e = 0; e < EDIM; ++e) dot += yn[pi][e] * ev[e];
                const float sc = h2 - dot;
                if (sc < mind[pi]) { mind[pi] = sc; mini[pi] = v; }
            }
        }
    }
    for (int m = 1; m < 64; m <<= 1) {
        #pragma unroll
        for (int pi = 0; pi < 4; ++pi) {
            const float ov = __shfl_xor(mind[pi], m);
            const int   oi = __shfl_xor(mini[pi], m);
            if (ov < mind[pi] || (ov == mind[pi] && oi < mini[pi])) { mind[pi] = ov; mini[pi] = oi; }
        }
    }
    if (lane == 0) {
        #pragma unroll
        for (int pi = 0; pi < 4; ++pi) codes[gbase + pi] = mini[pi];
    }
}

// ---------------- Merged conversions: enc->encB (bf16, row-packed) ; tno->tnoT (bf16, transposed)
__global__ __launch_bounds__(256) void convert_kernel(
    const float* __restrict__ enc, const float* __restrict__ tno,
    unsigned short* __restrict__ encB, unsigned short* __restrict__ tnoT)
{
    __shared__ float tile[32][33];
    const int bid = blockIdx.x;
    const int tid = threadIdx.x;
    if (bid < 2048) {
        // enc: 4 rows per block, 64 lanes x 8 f32 per row
        const int m = bid * 4 + (tid >> 6);
        const int d = (tid & 63) * 8;
        bf16x8 o;
        if (m < MROWS) {
            const int b = m / 511, t = m - b * 511;
            const float4 f0 = *(const float4*)&enc[((size_t)(b * 512 + t)) * ENCD + d];
            const float4 f1 = *(const float4*)&enc[((size_t)(b * 512 + t)) * ENCD + d + 4];
            o[0] = f2bf(f0.x); o[1] = f2bf(f0.y); o[2] = f2bf(f0.z); o[3] = f2bf(f0.w);
            o[4] = f2bf(f1.x); o[5] = f2bf(f1.y); o[6] = f2bf(f1.z); o[7] = f2bf(f1.w);
        } else {
            o = (bf16x8){0,0,0,0,0,0,0,0};
        }
        *(bf16x8*)&encB[(size_t)m * ENCD + d] = o;
    } else {
        const int bid2 = bid - 2048;               // 0..4095
        const int n0 = (bid2 & 255) * 32;
        const int k0 = (bid2 >> 8) * 32;
        const int tx = tid & 31, ty = tid >> 5;    // 32 x 8
        #pragma unroll
        for (int i = 0; i < 4; ++i)
            tile[ty + 8 * i][tx] = tno[(size_t)(k0 + ty + 8 * i) * NEMB + n0 + tx];
        __syncthreads();
        #pragma unroll
        for (int i = 0; i < 4; ++i)
            tnoT[(size_t)(n0 + ty + 8 * i) * ENCD + k0 + tx] = f2bf(tile[tx][ty + 8 * i]);
    }
}

// ---------------- Kernel B: bf16 MFMA GEMM 256x256 tile, 8 waves, BK=32, 2-phase dbuf ----
__global__ __launch_bounds__(512, 2) void logits_mfma(
    const unsigned short* __restrict__ encB, const unsigned short* __restrict__ tnoT,
    const int* __restrict__ codes,
    float* __restrict__ pm, float* __restrict__ ps, int* __restrict__ pidx,
    float* __restrict__ tgtlog)
{
    // arena[buf]: rows 0..255 = A (256 x 32 bf16), rows 256..511 = B. 2 x 32 KB = 64 KB.
    __shared__ __align__(16) unsigned short arena[2][512 * 32];

    const int tid  = threadIdx.x;
    const int lane = tid & 63;
    const int wave = tid >> 6;           // 0..7
    const int wrM = wave >> 2;           // 0..1 -> row offset 128
    const int wcN = wave & 3;            // 0..3 -> col offset 64

    // XCD mapping: each XCD owns 4 mt rows entirely; vt sweeps within.
    const int bid = blockIdx.x;          // 0..1023
    const int xcd = bid & 7;
    const int idx = bid >> 3;            // 0..127
    const int mt  = xcd * 4 + (idx & 3); // 0..31
    const int vt  = idx >> 2;            // 0..31
    const int m0 = mt * 256, n0 = vt * 256;

    // staging: rows of 32 bf16 (64B) in 4 chunks of 16B; involution slot = chunk ^ ((row>>1)&3)
    const int rb  = lane >> 2;                               // 0..15
    const int gc8 = ((lane & 3) ^ ((lane >> 3) & 3)) * 8;    // pre-swizzled source chunk
    const size_t abase = (size_t)(m0 + wave * 32 + rb) * ENCD + gc8;
    const size_t bbase = (size_t)(n0 + wave * 32 + rb) * ENCD + gc8;

#define STAGE(t, buf)                                                               \
    {                                                                               \
        const int k0s = (t) * 32;                                                   \
        gl_lds16(encB + abase + k0s,             &arena[buf][(wave * 32) * 32]);    \
        gl_lds16(encB + abase + 16 * ENCD + k0s, &arena[buf][(wave * 32 + 16) * 32]);\
        gl_lds16(tnoT + bbase + k0s,             &arena[buf][(256 + wave * 32) * 32]);\
        gl_lds16(tnoT + bbase + 16 * ENCD + k0s, &arena[buf][(256 + wave * 32 + 16) * 32]);\
    }

    f32x4 acc[8][4];
    #pragma unroll
    for (int i = 0; i < 8; ++i)
        #pragma unroll
        for (int j = 0; j < 4; ++j)
            acc[i][j] = (f32x4){0.f, 0.f, 0.f, 0.f};

    const int l15 = lane & 15, q = lane >> 4;
    const int ca = (q ^ ((l15 >> 1) & 3)) * 8;   // swizzled read chunk (elems)

    STAGE(0, 0);

    #pragma unroll
    for (int t = 0; t < 16; ++t) {
        asm volatile("s_waitcnt vmcnt(0)" ::: "memory");
        __builtin_amdgcn_s_barrier();
        __builtin_amdgcn_sched_barrier(0);
        if (t + 1 < 16) STAGE(t + 1, (t + 1) & 1);
        const unsigned short* buf = arena[t & 1];
        bf16x8 a[8], b[4];
        #pragma unroll
        for (int mi = 0; mi < 8; ++mi)
            a[mi] = *(const bf16x8*)&buf[(wrM * 128 + mi * 16 + l15) * 32 + ca];
        #pragma unroll
        for (int ni = 0; ni < 4; ++ni)
            b[ni] = *(const bf16x8*)&buf[(256 + wcN * 64 + ni * 16 + l15) * 32 + ca];
        __builtin_amdgcn_s_setprio(1);
        #pragma unroll
        for (int mi = 0; mi < 8; ++mi)
            #pragma unroll
            for (int ni = 0; ni < 4; ++ni)
                acc[mi][ni] = __builtin_amdgcn_mfma_f32_16x16x32_bf16(a[mi], b[ni], acc[mi][ni], 0, 0, 0);
        __builtin_amdgcn_s_setprio(0);
    }
#undef STAGE

    // Epilogue: per-row partial max / first-argmax / sumexp over this block's 256 cols.
    __syncthreads();                       // all LDS reads of the loop are ordered before this
    float* redM = (float*)&arena[0][0];    // [4][256]
    float* redS = redM + 4 * 256;
    int*   redI = (int*)(redS + 4 * 256);

    #pragma unroll
    for (int mi = 0; mi < 8; ++mi) {
        #pragma unroll
        for (int r = 0; r < 4; ++r) {
            const int rl = wrM * 128 + mi * 16 + q * 4 + r;   // local row 0..255
            float lm = -INFINITY; int li = 0;
            #pragma unroll
            for (int ni = 0; ni < 4; ++ni) {
                const float v = acc[mi][ni][r];
                const int col = wcN * 64 + ni * 16 + l15;
                if (v > lm) { lm = v; li = col; }             // ascending col per lane
            }
            #pragma unroll
            for (int mk = 8; mk >= 1; mk >>= 1) {
                const float ov = __shfl_xor(lm, mk);
                const int   oi = __shfl_xor(li, mk);
                if (ov > lm || (ov == lm && oi < li)) { lm = ov; li = oi; }
            }
            float le = 0.f;
            #pragma unroll
            for (int ni = 0; ni < 4; ++ni) le += __expf(acc[mi][ni][r] - lm);
            #pragma unroll
            for (int mk = 8; mk >= 1; mk >>= 1) le += __shfl_xor(le, mk);

            if (l15 == 0) { redM[wcN * 256 + rl] = lm; redS[wcN * 256 + rl] = le; redI[wcN * 256 + rl] = li; }

            const int mg = m0 + rl;
            if (mg < MROWS) {
                const int bb = mg / 511, tt = mg - bb * 511;
                const int tv = codes[bb * NPOS + tt + 1];
                const int rel = tv - n0 - wcN * 64;
                #pragma unroll
                for (int ni = 0; ni < 4; ++ni) {
                    if (rel >= ni * 16 && rel < ni * 16 + 16 && (rel & 15) == l15)
                        tgtlog[mg] = acc[mi][ni][r];
                }
            }
        }
    }
    __syncthreads();
    if (tid < 256) {
        const int rl = tid;
        const int mg = m0 + rl;
        if (mg < MROWS) {
            float gm = -INFINITY; int gi = 0;
            float S = 0.f;
            float gM[4]; int gI[4]; float gS[4];
            #pragma unroll
            for (int g2 = 0; g2 < 4; ++g2) { gM[g2] = redM[g2 * 256 + rl]; gS[g2] = redS[g2 * 256 + rl]; gI[g2] = redI[g2 * 256 + rl]; }
            #pragma unroll
            for (int g2 = 0; g2 < 4; ++g2) {
                const int colb = g2 * 64;
                if (gM[g2] > gm || (gM[g2] == gm && colb + gI[g2] < gi)) { gm = gM[g2]; gi = colb + gI[g2]; }
            }
            #pragma unroll
            for (int g2 = 0; g2 < 4; ++g2) S += gS[g2] * __expf(gM[g2] - gm);
            pm[(size_t)vt * MPAD + mg]   = gm;
            ps[(size_t)vt * MPAD + mg]   = S;
            pidx[(size_t)vt * MPAD + mg] = n0 + gi;
        }
    }
}

// ---------------- Phase 2: combine per-row + block reduce + last-block finalize ----------------
__global__ __launch_bounds__(256) void combine_kernel(
    const float* __restrict__ pm, const float* __restrict__ ps,
    const int* __restrict__ pidx, const float* __restrict__ tgtlog,
    const int* __restrict__ codes, const int* __restrict__ lens,
    int* __restrict__ presence, int* __restrict__ sctrl,
    float* __restrict__ out)
{
    float* partials = (float*)(sctrl + 64);   // 32 blocks x 3
    const int tid = threadIdx.x;
    const int g = blockIdx.x * 256 + tid;
    float nll = 0.f, corr = 0.f, mfv = 0.f;
    if (g < MROWS) {
        float gm = -INFINITY; int gi = 0;
        #pragma unroll 8
        for (int nt = 0; nt < NVT; ++nt) {
            const float v = pm[(size_t)nt * MPAD + g];
            if (v > gm) { gm = v; gi = pidx[(size_t)nt * MPAD + g]; }
        }
        float S = 0.f;
        #pragma unroll 8
        for (int nt = 0; nt < NVT; ++nt) S += ps[(size_t)nt * MPAD + g] * __expf(pm[(size_t)nt * MPAD + g] - gm);
        const float lse = gm + logf(S);
        const int b = g / 511, t = g - b * 511;
        const int tv = codes[b * NPOS + t + 1];
        const int L = lens[b];
        const int s = t + 1;
        const bool mf = (s < (L / 4)) && (4 * s + 3 < L);
        if (mf) {
            nll = lse - tgtlog[g];
            corr = (gi == tv) ? 1.f : 0.f;
            mfv = 1.f;
            if (atomicExch(&presence[tv], 1) == 0) atomicAdd(&sctrl[1], 1);
        }
    }
    __shared__ float s0[256], s1[256], s2[256];
    s0[tid] = nll; s1[tid] = corr; s2[tid] = mfv;
    __syncthreads();
    for (int st = 128; st > 0; st >>= 1) {
        if (tid < st) { s0[tid] += s0[tid + st]; s1[tid] += s1[tid + st]; s2[tid] += s2[tid + st]; }
        __syncthreads();
    }
    if (tid == 0) {
        partials[blockIdx.x * 3 + 0] = s0[0];
        partials[blockIdx.x * 3 + 1] = s1[0];
        partials[blockIdx.x * 3 + 2] = s2[0];
        __threadfence();
        const int tk = atomicAdd(&sctrl[0], 1);
        if (tk == 31) {
            float tn = 0.f, tc = 0.f, tm = 0.f;
            for (int i = 0; i < 32; ++i) {
                tn += atomicAdd(&partials[i * 3 + 0], 0.f);
                tc += atomicAdd(&partials[i * 3 + 1], 0.f);
                tm += atomicAdd(&partials[i * 3 + 2], 0.f);
            }
            const float uq = (float)atomicAdd(&sctrl[1], 0);
            out[0] = tn / tm;
            out[1] = tc / tm;
            out[2] = tm;
            out[3] = uq;
        }
    }
}

extern "C" void kernel_launch(void* const* d_in, const int* in_sizes, int n_in,
                              void* d_out, int out_size, void* d_ws, size_t ws_size,
                              hipStream_t stream) {
    const float* feats = (const float*)d_in[0];
    const int*   lens  = (const int*)d_in[1];
    const float* enc   = (const float*)d_in[2];
    const float* proj  = (const float*)d_in[3];
    const float* emb   = (const float*)d_in[4];
    const float* tno   = (const float*)d_in[5];
    float* out = (float*)d_out;

    int* codes          = (int*)d_ws;                        // 8192
    int* presence       = codes + MPAD;                      // 8192
    int* sctrl          = presence + MPAD;                   // 64 ctrl + 96 partials = 160
    float* pm           = (float*)(sctrl + 160);             // 32*8192
    float* ps           = pm + (size_t)NVT * MPAD;           // 32*8192
    int* pidx           = (int*)(ps + (size_t)NVT * MPAD);   // 32*8192
    float* tgtlog       = (float*)(pidx + (size_t)NVT * MPAD); // 8192
    unsigned short* encB = (unsigned short*)(tgtlog + MPAD); // 8192*512
    unsigned short* tnoT = encB + (size_t)MPAD * ENCD;       // 8192*512

    hipLaunchKernelGGL(codes_kernel, dim3(512), dim3(256), 0, stream, feats, proj, emb, codes, presence, sctrl);
    hipLaunchKernelGGL(convert_kernel, dim3(2048 + 4096), dim3(256), 0, stream, enc, tno, encB, tnoT);
    hipLaunchKernelGGL(logits_mfma, dim3(1024), dim3(512), 0, stream, encB, tnoT, codes, pm, ps, pidx, tgtlog);
    hipLaunchKernelGGL(combine_kernel, dim3(32), dim3(256), 0, stream,
                       pm, ps, pidx, tgtlog, codes, lens, presence, sctrl, out);
}